// Round 18
// baseline (105.235 us; speedup 1.0000x reference)
//
#include <hip/hip_runtime.h>

// Profile-HMM forward + KLD, MI355X.
// v17 = v16 EXACTLY (linear-space, 2 cols/step, compressed sender-dot
// boundary channel, per-lane exponent E) with one change: LAUNCH GEOMETRY.
// 32 blocks x 1024 threads = 16 waves/CU = 4 waves/SIMD. Every prior
// version ran 1 wave/SIMD (512 waves on 1024 SIMDs), so each DPP-dependent
// stall (~60-80 cyc) was raw exposed latency. Co-resident waves let the CU
// scheduler fill one wave's stall with another wave's issue (m114
// mechanism). 4 waves x ~138 issue-cyc/step ~= one wave's 552-cyc span ->
// stalls ~fully hidden, 4 batches per span. Waves are fully independent
// (one batch each, no __syncthreads, shuffles are wave-scoped).

constexpr float LOG2E = 1.4426950408889634f;
constexpr float LN2   = 0.6931471805599453f;

__device__ __forceinline__ float exp2_hw(float x){ return __builtin_amdgcn_exp2f(x); }
__device__ __forceinline__ float log2_hw(float x){ return __builtin_amdgcn_logf(x); }
__device__ __forceinline__ float ldx(float x,int e){ return __builtin_amdgcn_ldexpf(x,e); }
__device__ __forceinline__ int   fxe(float x){ return __builtin_amdgcn_frexp_expf(x); }
// DPP wave_shr:1 — lane i gets lane i-1's src; lane 0 gets old_.
__device__ __forceinline__ int   dppi(int o,int s){ return __builtin_amdgcn_update_dpp(o,s,0x138,0xF,0xF,false); }
__device__ __forceinline__ float dppf(float o,float s){ return __int_as_float(dppi(__float_as_int(o),__float_as_int(s))); }

// One 2-col step: cols c = 2*(SM1+1)-1-2i, c+1.
// Received channels (from lane i-1, row 2i):
//   qdMm: dotM @ col c   -> consumed NEXT... (see v16 comments)
//   qdMe: dotM @ col c+1 -> saved (pdM), consumed NEXT step
//   qdDm: dotD @ col c   -> nD1;  qdDe: dotD @ col c+1 -> nD1b
// sq = 2^(qE - E) hoisted per 4-step group (E frozen between rescales).
#define STEP(FRESH, ISS1, MASKED, SM1) do {                                    \
    const float qdMm = dppf(0.0f, xdMm);                                       \
    const float qdMe = dppf(0.0f, xdMe);                                       \
    const float qdDm = dppf(0.0f, xdDm);                                       \
    const float qdDe = dppf(0.0f, xdDe);                                       \
    const int   qsym = dppi((FRESH), symq);                                    \
    const float v   = (ISS1) ? q1g : gg * u;       /* fI0[2s-1] */             \
    const float nI1 = fmaf(tmi1, cMx, tii1 * cIx);                             \
    const float nI2 = fmaf(tmi2, cMy, tii2 * cIy);                             \
    float dM_c1 = qdMm * sq;                                                   \
    const float dD_c  = qdDm * sq;     /* lane0: 0*1 = 0 = row-0 dotD */       \
    const float dD_c1 = qdDe * sq;                                             \
    const float dM_sv = qdMe * sq;                                             \
    float dP = pdM;                                                            \
    /* lane-0 virtual row 0: dotM = tmm0*fM0 + tim0*fI0 (fD0-term = 0) */      \
    const float z0 = fmaf(tim0, ldx(u, EI0 - E),                               \
                          (ISS1) ? ldx(tmm0, -E) : 0.0f);                      \
    const float z1 = tim0 * ldx(v, EI0 - E);                                   \
    if (lane0) { dP = z0; dM_c1 = z1; }                                        \
    const bool ba = (qsym & 1) != 0, bb = (qsym & 2) != 0;                     \
    const bool bc = (qsym & 4) != 0, bd = (qsym & 8) != 0;                     \
    const float e1c = bb ? (ba ? el1.w : el1.z) : (ba ? el1.y : el1.x);        \
    const float e2c = bb ? (ba ? el2.w : el2.z) : (ba ? el2.y : el2.x);        \
    const float e1d = bd ? (bc ? el1.w : el1.z) : (bc ? el1.y : el1.x);        \
    const float e2d = bd ? (bc ? el2.w : el2.z) : (bc ? el2.y : el2.x);        \
    /* ---- col c ---- */                                                      \
    const float nM1 = e1c * dP;                                                \
    const float nM2 = e2c * fmaf(tdm1, cDx, fmaf(tim1, cIx, tmm1 * cMx));      \
    const float nD1 = dD_c;                                                    \
    const float nD2 = fmaf(tmd1, nM1, tdd1 * nD1);                             \
    /* ---- col c+1 ---- */                                                    \
    const float nM1b = e1d * dM_c1;                                            \
    const float nI1b = fmaf(tmi1, nM1, tii1 * nI1);                            \
    const float nI2b = fmaf(tmi2, nM2, tii2 * nI2);                            \
    const float nD1b = dD_c1;                                                  \
    const float nM2b = e2d * fmaf(tdm1, nD1, fmaf(tim1, nI1, tmm1 * nM1));     \
    const float nD2b = fmaf(tmd1, nM1b, tdd1 * nD1b);                          \
    /* ---- sender dots for lane i+1 (row 2i+2 coefficients) ---- */           \
    const float ndMm = fmaf(t2mm, nM2,  fmaf(t2im, nI2,  t2dm * nD2));         \
    const float ndMe = fmaf(t2mm, nM2b, fmaf(t2im, nI2b, t2dm * nD2b));        \
    const float ndDm = fmaf(t2md, nM2,  t2dd * nD2);                           \
    const float ndDe = fmaf(t2md, nM2b, t2dd * nD2b);                          \
    /* ---- commit ---- */                                                     \
    xdMm = ndMm; xdDm = ndDm; xdDe = ndDe;  /* consumed only when act */       \
    if (MASKED) {                                                              \
        const bool act = ((unsigned)((SM1) - i)) < 128u;                       \
        cMx = act ? nM1b : cMx;  cMy = act ? nM2b : cMy;                       \
        cIx = act ? nI1b : cIx;  cIy = act ? nI2b : cIy;                       \
        cDx = act ? nD1b : cDx;  cDy = act ? nD2b : cDy;                       \
        xdMe = act ? ndMe : xdMe;   /* pre-active: frozen col-0 end-dot */     \
    } else {                                                                   \
        cMx = nM1b; cMy = nM2b; cIx = nI1b; cIy = nI2b; cDx = nD1b; cDy = nD2b;\
        xdMe = ndMe;                                                           \
    }                                                                          \
    pdM = dM_sv;                                                               \
    symq = qsym;                                                               \
    u = gg * v;                                    /* fI0[2s] */               \
} while (0)

#define RESCALE do {                                                           \
    const float anc = fmaxf(fmaxf(fmaxf(cMx, cMy), fmaxf(cIx, cIy)),           \
                            fmaxf(cDx, cDy));                                  \
    const int e = fxe(anc);                                                    \
    E += e;                                                                    \
    const float sE = ldx(1.0f, -e);                                            \
    cMx *= sE; cMy *= sE; cIx *= sE; cIy *= sE; cDx *= sE; cDy *= sE;          \
    xdMm *= sE; xdMe *= sE; xdDm *= sE; xdDe *= sE; pdM *= sE;                 \
    const int eI = fxe(u); EI0 += eI; u = ldx(u, -eI);                         \
} while (0)

// transitions: (B, 129, 7)  M2M=0 M2I=1 M2D=2 I2M=3 I2I=4 D2M=5 D2D=6
// emissions:   (B, 128, 4);  tokens: (B, 256) int32 in [0,4)
__global__ __launch_bounds__(1024) void phmm_fwd(const int* __restrict__ tokens,
                                                 const float* __restrict__ trans,
                                                 const float* __restrict__ emis,
                                                 float* __restrict__ nll_out)
{
    const int b = blockIdx.x * 16 + (threadIdx.x >> 6);  // one batch per wave
    const int i = threadIdx.x & 63;
    const bool lane0 = (i == 0);

    const float* ab = trans + (size_t)b * 903;
    const int r0 = (2*i)*7, r1 = (2*i+1)*7, r2 = (2*i+2)*7;

    // Linear-space params.
    const float tmm0 = exp2_hw(ab[r0+0]*LOG2E);      // lane-0 synthesis only
    const float tim0 = exp2_hw(ab[r0+3]*LOG2E);
    const float tmm1 = exp2_hw(ab[r1+0]*LOG2E);
    const float tim1 = exp2_hw(ab[r1+3]*LOG2E);
    const float tdm1 = exp2_hw(ab[r1+5]*LOG2E);
    const float tmd1 = exp2_hw(ab[r1+2]*LOG2E);
    const float tdd1 = exp2_hw(ab[r1+6]*LOG2E);
    const float tmi1 = 0.25f*exp2_hw(ab[r1+1]*LOG2E);
    const float tii1 = 0.25f*exp2_hw(ab[r1+4]*LOG2E);
    const float tmi2 = 0.25f*exp2_hw(ab[r2+1]*LOG2E);
    const float tii2 = 0.25f*exp2_hw(ab[r2+4]*LOG2E);
    // Sender-dot coefficients: row 2i+2 = receiver's (k-1) row.
    const float t2mm = exp2_hw(ab[r2+0]*LOG2E);
    const float t2im = exp2_hw(ab[r2+3]*LOG2E);
    const float t2dm = exp2_hw(ab[r2+5]*LOG2E);
    const float t2md = exp2_hw(ab[r2+2]*LOG2E);
    const float t2dd = exp2_hw(ab[r2+6]*LOG2E);
    const float q1g  = 0.25f*exp2_hw(ab[1]*LOG2E);   // fI0[1]
    const float gg   = 0.25f*exp2_hw(ab[4]*LOG2E);   // fI0 geometric link

    const float4* eb = (const float4*)(emis + (size_t)b*512);
    float4 el1 = eb[2*i], el2 = eb[2*i+1];
    el1.x=exp2_hw(el1.x*LOG2E); el1.y=exp2_hw(el1.y*LOG2E);
    el1.z=exp2_hw(el1.z*LOG2E); el1.w=exp2_hw(el1.w*LOG2E);
    el2.x=exp2_hw(el2.x*LOG2E); el2.y=exp2_hw(el2.y*LOG2E);
    el2.z=exp2_hw(el2.z*LOG2E); el2.w=exp2_hw(el2.w*LOG2E);

    const int4 ts = ((const int4*)(tokens + (size_t)b*256))[i];

    // Col-0 delete chain, closed form (log2 prefix scan; wave-scoped shuffles).
    const float ldd0 = ab[r0+6]*LOG2E;
    const float ldd1 = ab[r1+6]*LOG2E;
    const float lmd0b = ab[2]*LOG2E;
    float incl = (lane0 ? 0.0f : ldd0) + ldd1;
    #pragma unroll
    for (int d = 1; d < 64; d <<= 1) {
        float t = __shfl_up(incl, d);
        if (i >= d) incl += t;
    }
    float exPre = __shfl_up(incl, 1);
    if (lane0) exPre = 0.0f;
    const float g1 = lmd0b + exPre + (lane0 ? 0.0f : ldd0); // log2 fD[2i+1][0]
    const float g2 = g1 + ldd1;                             // log2 fD[2i+2][0]

    int E = (int)floorf(fmaxf(g1, g2));
    float cMx = 0.0f, cMy = 0.0f, cIx = 0.0f, cIy = 0.0f;
    float cDx = exp2_hw(g1 - (float)E), cDy = exp2_hw(g2 - (float)E);
    // Export regs. xdMe init = col-0 end-dot (fM[2i+2][0]=0, fI=0):
    float xdMm = 0.0f, xdDm = 0.0f, xdDe = 0.0f;
    float xdMe = t2dm * cDy;
    float pdM = 0.0f;                 // never consumed before first real save
    float u = 0.0f; int EI0 = 0;      // fI0 chain (wave-replicated)
    int symq = 0;

    // 48 groups x 4 steps (s = 1..192). Fill g<16 (masked), steady 16..31
    // (mask-free), drain 32..47 (masked, no tokens). qE/sq hoisted per group.
    #pragma unroll 1
    for (int g = 0; g < 16; ++g) {          // FILL
        const int qE = dppi(E, E);
        const float sq = ldx(1.0f, qE - E);
        const int a0 = __builtin_amdgcn_readlane(ts.x, 2*g);
        const int a1 = __builtin_amdgcn_readlane(ts.y, 2*g);
        const int a2 = __builtin_amdgcn_readlane(ts.z, 2*g);
        const int a3 = __builtin_amdgcn_readlane(ts.w, 2*g);
        const int b0 = __builtin_amdgcn_readlane(ts.x, 2*g+1);
        const int b1 = __builtin_amdgcn_readlane(ts.y, 2*g+1);
        const int b2 = __builtin_amdgcn_readlane(ts.z, 2*g+1);
        const int b3 = __builtin_amdgcn_readlane(ts.w, 2*g+1);
        STEP(a0 | (a1 << 2), g == 0, 1, 4*g);
        STEP(a2 | (a3 << 2), false,  1, 4*g + 1);
        STEP(b0 | (b1 << 2), false,  1, 4*g + 2);
        STEP(b2 | (b3 << 2), false,  1, 4*g + 3);
        RESCALE;
    }
    #pragma unroll 1
    for (int g = 16; g < 32; ++g) {         // STEADY (all lanes active)
        const int qE = dppi(E, E);
        const float sq = ldx(1.0f, qE - E);
        const int a0 = __builtin_amdgcn_readlane(ts.x, 2*g);
        const int a1 = __builtin_amdgcn_readlane(ts.y, 2*g);
        const int a2 = __builtin_amdgcn_readlane(ts.z, 2*g);
        const int a3 = __builtin_amdgcn_readlane(ts.w, 2*g);
        const int b0 = __builtin_amdgcn_readlane(ts.x, 2*g+1);
        const int b1 = __builtin_amdgcn_readlane(ts.y, 2*g+1);
        const int b2 = __builtin_amdgcn_readlane(ts.z, 2*g+1);
        const int b3 = __builtin_amdgcn_readlane(ts.w, 2*g+1);
        STEP(a0 | (a1 << 2), false, 0, 4*g);
        STEP(a2 | (a3 << 2), false, 0, 4*g + 1);
        STEP(b0 | (b1 << 2), false, 0, 4*g + 2);
        STEP(b2 | (b3 << 2), false, 0, 4*g + 3);
        RESCALE;
    }
    #pragma unroll 1
    for (int g = 32; g < 48; ++g) {         // DRAIN (no fresh tokens needed)
        const int qE = dppi(E, E);
        const float sq = ldx(1.0f, qE - E);
        STEP(0, false, 1, 4*g);
        STEP(0, false, 1, 4*g + 1);
        STEP(0, false, 1, 4*g + 2);
        STEP(0, false, 1, 4*g + 3);
        RESCALE;
    }

    // lane 63: xdMe (frozen after its last active step, rescales tracked by E)
    // = a[128][M2M]*fM[128][256] + a[128][I2M]*fI + a[128][D2M]*fD = final sum.
    if (i == 63) nll_out[b] = -(log2_hw(xdMe) + (float)E)*LN2;
}

__global__ __launch_bounds__(256) void phmm_finish(const float* __restrict__ nll,
                                                   const float* __restrict__ mus,
                                                   const float* __restrict__ logvars,
                                                   float* __restrict__ out)
{
    const int tid = threadIdx.x;
    float acc = 0.0f;
    for (int idx = tid; idx < 512; idx += 256) acc += nll[idx];
    for (int idx = tid; idx < 8192; idx += 256) {
        const float mu = mus[idx], lv = logvars[idx];
        acc -= 0.5f * (1.0f + lv - mu * mu - exp2_hw(lv * LOG2E));
    }
    #pragma unroll
    for (int off = 32; off >= 1; off >>= 1) acc += __shfl_down(acc, off);
    __shared__ float red[4];
    if ((tid & 63) == 0) red[tid >> 6] = acc;
    __syncthreads();
    if (tid == 0) out[0] = (red[0] + red[1] + red[2] + red[3]) * (1.0f / 512.0f);
}

extern "C" void kernel_launch(void* const* d_in, const int* in_sizes, int n_in,
                              void* d_out, int out_size, void* d_ws, size_t ws_size,
                              hipStream_t stream)
{
    const int*   tokens  = (const int*)d_in[0];   // (512, 256) int32
    const float* trans   = (const float*)d_in[1]; // (512, 129, 7) f32
    const float* emis    = (const float*)d_in[2]; // (512, 128, 4) f32
    const float* mus     = (const float*)d_in[3]; // (512, 16) f32
    const float* logvars = (const float*)d_in[4]; // (512, 16) f32
    float* nll = (float*)d_ws;                    // 512 floats scratch

    phmm_fwd<<<dim3(32), dim3(1024), 0, stream>>>(tokens, trans, emis, nll);
    phmm_finish<<<dim3(1), dim3(256), 0, stream>>>(nll, mus, logvars, (float*)d_out);
}

// Round 20
// 41.561 us; speedup vs baseline: 2.5321x; 2.5321x over previous
//
#include <hip/hip_runtime.h>

// Profile-HMM forward + KLD, MI355X.
// v19 = v18 (software-pipelined DPP channel) with the scale-epoch fix:
// RESCALE moved BEFORE the group's last TAIL. Invariant: every tail-captured
// value shares one scale epoch with the per-group qE_c. v18's bug: the
// boundary tail captured PRE-rescale exports+qE, but mid-group tails then
// captured POST-rescale exports that steps 1-3 converted with the stale
// pre-rescale sq -> off by 2^(e_nb) per group, compounding to inf.
// Now: boundary tail (after RESCALE) captures post-rescale exports with
// post-rescale qE_c; mid-group exports stay in that same frozen scale.

constexpr float LOG2E = 1.4426950408889634f;
constexpr float LN2   = 0.6931471805599453f;

__device__ __forceinline__ float exp2_hw(float x){ return __builtin_amdgcn_exp2f(x); }
__device__ __forceinline__ float log2_hw(float x){ return __builtin_amdgcn_logf(x); }
__device__ __forceinline__ float ldx(float x,int e){ return __builtin_amdgcn_ldexpf(x,e); }
__device__ __forceinline__ int   fxe(float x){ return __builtin_amdgcn_frexp_expf(x); }
// DPP wave_shr:1 — lane i gets lane i-1's src; lane 0 gets old_.
__device__ __forceinline__ int   dppi(int o,int s){ return __builtin_amdgcn_update_dpp(o,s,0x138,0xF,0xF,false); }
__device__ __forceinline__ float dppf(float o,float s){ return __int_as_float(dppi(__float_as_int(o),__float_as_int(s))); }
__device__ __forceinline__ int   rl(int v, int sel){ return __builtin_amdgcn_readlane(v, sel); }

// Body of one 2-col step: consumes CARRIED channel values (qd*_c, qsym_c)
// issued at the previous step's tail. Cols c = 2*(SM1+1)-1-2i, c+1.
#define STEP(ISS1, MASKED, SM1) do {                                           \
    const float v   = (ISS1) ? q1g : gg * u;       /* fI0[2s-1] */             \
    const float nI1 = fmaf(tmi1, cMx, tii1 * cIx);                             \
    const float nI2 = fmaf(tmi2, cMy, tii2 * cIy);                             \
    float dM_c1 = qdMm_c * sq;                                                 \
    const float dD_c  = qdDm_c * sq;    /* lane0: 0*sq = 0 = row-0 dotD */     \
    const float dD_c1 = qdDe_c * sq;                                           \
    const float dM_sv = qdMe_c * sq;                                           \
    float dP = pdM;                                                            \
    /* lane-0 virtual row 0: dotM = tmm0*fM0 + tim0*fI0 (fD0-term = 0) */      \
    const float z0 = fmaf(tim0, ldx(u, EI0 - E),                               \
                          (ISS1) ? ldx(tmm0, -E) : 0.0f);                      \
    const float z1 = tim0 * ldx(v, EI0 - E);                                   \
    if (lane0) { dP = z0; dM_c1 = z1; }                                        \
    const int qsym = qsym_c;                                                   \
    const bool ba = (qsym & 1) != 0, bb = (qsym & 2) != 0;                     \
    const bool bc = (qsym & 4) != 0, bd = (qsym & 8) != 0;                     \
    const float e1c = bb ? (ba ? el1.w : el1.z) : (ba ? el1.y : el1.x);        \
    const float e2c = bb ? (ba ? el2.w : el2.z) : (ba ? el2.y : el2.x);        \
    const float e1d = bd ? (bc ? el1.w : el1.z) : (bc ? el1.y : el1.x);        \
    const float e2d = bd ? (bc ? el2.w : el2.z) : (bc ? el2.y : el2.x);        \
    /* ---- col c ---- */                                                      \
    const float nM1 = e1c * dP;                                                \
    const float nM2 = e2c * fmaf(tdm1, cDx, fmaf(tim1, cIx, tmm1 * cMx));      \
    const float nD1 = dD_c;                                                    \
    const float nD2 = fmaf(tmd1, nM1, tdd1 * nD1);                             \
    /* ---- col c+1 ---- */                                                    \
    const float nM1b = e1d * dM_c1;                                            \
    const float nI1b = fmaf(tmi1, nM1, tii1 * nI1);                            \
    const float nI2b = fmaf(tmi2, nM2, tii2 * nI2);                            \
    const float nD1b = dD_c1;                                                  \
    const float nM2b = e2d * fmaf(tdm1, nD1, fmaf(tim1, nI1, tmm1 * nM1));     \
    const float nD2b = fmaf(tmd1, nM1b, tdd1 * nD1b);                          \
    /* ---- sender dots for lane i+1 (row 2i+2 coefficients) ---- */           \
    const float ndMm = fmaf(t2mm, nM2,  fmaf(t2im, nI2,  t2dm * nD2));         \
    const float ndMe = fmaf(t2mm, nM2b, fmaf(t2im, nI2b, t2dm * nD2b));        \
    const float ndDm = fmaf(t2md, nM2,  t2dd * nD2);                           \
    const float ndDe = fmaf(t2md, nM2b, t2dd * nD2b);                          \
    /* ---- commit ---- */                                                     \
    xdMm = ndMm; xdDm = ndDm; xdDe = ndDe;                                     \
    if (MASKED) {                                                              \
        const bool act = ((unsigned)((SM1) - i)) < 128u;                       \
        cMx = act ? nM1b : cMx;  cMy = act ? nM2b : cMy;                       \
        cIx = act ? nI1b : cIx;  cIy = act ? nI2b : cIy;                       \
        cDx = act ? nD1b : cDx;  cDy = act ? nD2b : cDy;                       \
        xdMe = act ? ndMe : xdMe;   /* pre-active: frozen col-0 end-dot */     \
    } else {                                                                   \
        cMx = nM1b; cMy = nM2b; cIx = nI1b; cIy = nI2b; cDx = nD1b; cDy = nD2b;\
        xdMe = ndMe;                                                           \
    }                                                                          \
    pdM = dM_sv;                                                               \
    symq = qsym;                                                               \
    u = gg * v;                                    /* fI0[2s] */               \
} while (0)

// Tail: issue NEXT step's cross-lane ops on the just-committed exports.
// LASTG tails run AFTER RESCALE and also capture neighbor E (post-rescale),
// so captured values and qE_c share one scale epoch.
#define TAIL(FRESH_NEXT, LASTG) do {                                           \
    qdMm_c = dppf(0.0f, xdMm);                                                 \
    qdMe_c = dppf(0.0f, xdMe);                                                 \
    qdDm_c = dppf(0.0f, xdDm);                                                 \
    qdDe_c = dppf(0.0f, xdDe);                                                 \
    qsym_c = dppi((FRESH_NEXT), symq);                                         \
    if (LASTG) qE_c = dppi(E, E);                                              \
    __builtin_amdgcn_sched_barrier(0);                                         \
} while (0)

#define RESCALE do {                                                           \
    const float anc = fmaxf(fmaxf(fmaxf(cMx, cMy), fmaxf(cIx, cIy)),           \
                            fmaxf(cDx, cDy));                                  \
    const int e = fxe(anc);                                                    \
    E += e;                                                                    \
    const float sE = ldx(1.0f, -e);                                            \
    cMx *= sE; cMy *= sE; cIx *= sE; cIy *= sE; cDx *= sE; cDy *= sE;          \
    xdMm *= sE; xdMe *= sE; xdDm *= sE; xdDe *= sE; pdM *= sE;                 \
    const int eI = fxe(u); EI0 += eI; u = ldx(u, -eI);                         \
} while (0)

// transitions: (B, 129, 7)  M2M=0 M2I=1 M2D=2 I2M=3 I2I=4 D2M=5 D2D=6
// emissions:   (B, 128, 4);  tokens: (B, 256) int32 in [0,4)
__global__ __launch_bounds__(64, 1) void phmm_fwd(const int* __restrict__ tokens,
                                                  const float* __restrict__ trans,
                                                  const float* __restrict__ emis,
                                                  float* __restrict__ nll_out)
{
    const int b = blockIdx.x;
    const int i = threadIdx.x;
    const bool lane0 = (i == 0);

    const float* ab = trans + (size_t)b * 903;
    const int r0 = (2*i)*7, r1 = (2*i+1)*7, r2 = (2*i+2)*7;

    // Linear-space params.
    const float tmm0 = exp2_hw(ab[r0+0]*LOG2E);      // lane-0 synthesis only
    const float tim0 = exp2_hw(ab[r0+3]*LOG2E);
    const float tmm1 = exp2_hw(ab[r1+0]*LOG2E);
    const float tim1 = exp2_hw(ab[r1+3]*LOG2E);
    const float tdm1 = exp2_hw(ab[r1+5]*LOG2E);
    const float tmd1 = exp2_hw(ab[r1+2]*LOG2E);
    const float tdd1 = exp2_hw(ab[r1+6]*LOG2E);
    const float tmi1 = 0.25f*exp2_hw(ab[r1+1]*LOG2E);
    const float tii1 = 0.25f*exp2_hw(ab[r1+4]*LOG2E);
    const float tmi2 = 0.25f*exp2_hw(ab[r2+1]*LOG2E);
    const float tii2 = 0.25f*exp2_hw(ab[r2+4]*LOG2E);
    // Sender-dot coefficients: row 2i+2 = receiver's (k-1) row.
    const float t2mm = exp2_hw(ab[r2+0]*LOG2E);
    const float t2im = exp2_hw(ab[r2+3]*LOG2E);
    const float t2dm = exp2_hw(ab[r2+5]*LOG2E);
    const float t2md = exp2_hw(ab[r2+2]*LOG2E);
    const float t2dd = exp2_hw(ab[r2+6]*LOG2E);
    const float q1g  = 0.25f*exp2_hw(ab[1]*LOG2E);   // fI0[1]
    const float gg   = 0.25f*exp2_hw(ab[4]*LOG2E);   // fI0 geometric link

    const float4* eb = (const float4*)(emis + (size_t)b*512);
    float4 el1 = eb[2*i], el2 = eb[2*i+1];
    el1.x=exp2_hw(el1.x*LOG2E); el1.y=exp2_hw(el1.y*LOG2E);
    el1.z=exp2_hw(el1.z*LOG2E); el1.w=exp2_hw(el1.w*LOG2E);
    el2.x=exp2_hw(el2.x*LOG2E); el2.y=exp2_hw(el2.y*LOG2E);
    el2.z=exp2_hw(el2.z*LOG2E); el2.w=exp2_hw(el2.w*LOG2E);

    const int4 ts = ((const int4*)(tokens + (size_t)b*256))[i];

    // Col-0 delete chain, closed form (log2 prefix scan).
    const float ldd0 = ab[r0+6]*LOG2E;
    const float ldd1 = ab[r1+6]*LOG2E;
    const float lmd0b = ab[2]*LOG2E;
    float incl = (lane0 ? 0.0f : ldd0) + ldd1;
    #pragma unroll
    for (int d = 1; d < 64; d <<= 1) {
        float t = __shfl_up(incl, d);
        if (i >= d) incl += t;
    }
    float exPre = __shfl_up(incl, 1);
    if (lane0) exPre = 0.0f;
    const float g1 = lmd0b + exPre + (lane0 ? 0.0f : ldd0); // log2 fD[2i+1][0]
    const float g2 = g1 + ldd1;                             // log2 fD[2i+2][0]

    int E = (int)floorf(fmaxf(g1, g2));
    float cMx = 0.0f, cMy = 0.0f, cIx = 0.0f, cIy = 0.0f;
    float cDx = exp2_hw(g1 - (float)E), cDy = exp2_hw(g2 - (float)E);
    // Export regs. xdMe init = col-0 end-dot (fM[2i+2][0]=0, fI=0):
    float xdMm = 0.0f, xdDm = 0.0f, xdDe = 0.0f;
    float xdMe = t2dm * cDy;
    float pdM = 0.0f;
    float u = 0.0f; int EI0 = 0;      // fI0 chain (wave-replicated)
    int symq = 0;

    // Carried channel registers + prime (step (0,0)'s cross-lane ops).
    // Captured at init scale with qE_c at the same epoch — coherent.
    float qdMm_c, qdMe_c, qdDm_c, qdDe_c;
    int qsym_c, qE_c;
    {
        const int a0 = rl(ts.x, 0), a1 = rl(ts.y, 0);
        qdMm_c = dppf(0.0f, xdMm);
        qdMe_c = dppf(0.0f, xdMe);
        qdDm_c = dppf(0.0f, xdDm);
        qdDe_c = dppf(0.0f, xdDe);
        qsym_c = dppi(a0 | (a1 << 2), symq);
        qE_c   = dppi(E, E);
    }

    // 48 groups x 4 steps (s = 1..192). Fill g<16 (masked), steady 16..31
    // (mask-free), drain 32..47 (masked; junk tokens only reach inactive
    // cells). RESCALE precedes the last TAIL (scale-epoch coherence).
    #pragma unroll 1
    for (int g = 0; g < 16; ++g) {          // FILL
        const float sq = ldx(1.0f, qE_c - E);
        const int a2 = rl(ts.z, 2*g),   a3 = rl(ts.w, 2*g);       // (g,1)
        const int b0 = rl(ts.x, 2*g+1), b1 = rl(ts.y, 2*g+1);     // (g,2)
        const int b2 = rl(ts.z, 2*g+1), b3 = rl(ts.w, 2*g+1);     // (g,3)
        const int c0 = rl(ts.x, 2*g+2), c1 = rl(ts.y, 2*g+2);     // (g+1,0)
        STEP(g == 0, 1, 4*g + 0); TAIL(a2 | (a3 << 2), 0);
        STEP(false,  1, 4*g + 1); TAIL(b0 | (b1 << 2), 0);
        STEP(false,  1, 4*g + 2); TAIL(b2 | (b3 << 2), 0);
        STEP(false,  1, 4*g + 3);
        RESCALE;
        TAIL(c0 | (c1 << 2), 1);
    }
    #pragma unroll 1
    for (int g = 16; g < 32; ++g) {         // STEADY (all lanes active)
        const float sq = ldx(1.0f, qE_c - E);
        const int a2 = rl(ts.z, 2*g),   a3 = rl(ts.w, 2*g);
        const int b0 = rl(ts.x, 2*g+1), b1 = rl(ts.y, 2*g+1);
        const int b2 = rl(ts.z, 2*g+1), b3 = rl(ts.w, 2*g+1);
        const int c0 = rl(ts.x, (2*g+2) & 63), c1 = rl(ts.y, (2*g+2) & 63);
        STEP(false, 0, 4*g + 0); TAIL(a2 | (a3 << 2), 0);
        STEP(false, 0, 4*g + 1); TAIL(b0 | (b1 << 2), 0);
        STEP(false, 0, 4*g + 2); TAIL(b2 | (b3 << 2), 0);
        STEP(false, 0, 4*g + 3);
        RESCALE;
        TAIL(c0 | (c1 << 2), 1);
    }
    #pragma unroll 1
    for (int g = 32; g < 48; ++g) {         // DRAIN (tokens irrelevant)
        const float sq = ldx(1.0f, qE_c - E);
        STEP(false, 1, 4*g + 0); TAIL(0, 0);
        STEP(false, 1, 4*g + 1); TAIL(0, 0);
        STEP(false, 1, 4*g + 2); TAIL(0, 0);
        STEP(false, 1, 4*g + 3);
        RESCALE;
        TAIL(0, 1);
    }

    // lane 63: xdMe (frozen after its last active step, rescales tracked by E)
    // = a[128][M2M]*fM[128][256] + a[128][I2M]*fI + a[128][D2M]*fD.
    if (i == 63) nll_out[b] = -(log2_hw(xdMe) + (float)E)*LN2;
}

__global__ __launch_bounds__(256) void phmm_finish(const float* __restrict__ nll,
                                                   const float* __restrict__ mus,
                                                   const float* __restrict__ logvars,
                                                   float* __restrict__ out)
{
    const int tid = threadIdx.x;
    float acc = 0.0f;
    for (int idx = tid; idx < 512; idx += 256) acc += nll[idx];
    for (int idx = tid; idx < 8192; idx += 256) {
        const float mu = mus[idx], lv = logvars[idx];
        acc -= 0.5f * (1.0f + lv - mu * mu - exp2_hw(lv * LOG2E));
    }
    #pragma unroll
    for (int off = 32; off >= 1; off >>= 1) acc += __shfl_down(acc, off);
    __shared__ float red[4];
    if ((tid & 63) == 0) red[tid >> 6] = acc;
    __syncthreads();
    if (tid == 0) out[0] = (red[0] + red[1] + red[2] + red[3]) * (1.0f / 512.0f);
}

extern "C" void kernel_launch(void* const* d_in, const int* in_sizes, int n_in,
                              void* d_out, int out_size, void* d_ws, size_t ws_size,
                              hipStream_t stream)
{
    const int*   tokens  = (const int*)d_in[0];   // (512, 256) int32
    const float* trans   = (const float*)d_in[1]; // (512, 129, 7) f32
    const float* emis    = (const float*)d_in[2]; // (512, 128, 4) f32
    const float* mus     = (const float*)d_in[3]; // (512, 16) f32
    const float* logvars = (const float*)d_in[4]; // (512, 16) f32
    float* nll = (float*)d_ws;                    // 512 floats scratch

    phmm_fwd<<<dim3(512), dim3(64), 0, stream>>>(tokens, trans, emis, nll);
    phmm_finish<<<dim3(1), dim3(256), 0, stream>>>(nll, mus, logvars, (float*)d_out);
}

// Round 21
// 40.625 us; speedup vs baseline: 2.5904x; 1.0230x over previous
//
#include <hip/hip_runtime.h>

// Profile-HMM forward + KLD, MI355X — FINAL (= v16, measured best 40.79 µs).
// Linear-probability-space recurrence (all exps hoisted to init; zero
// transcendentals in the 192-step loop), one wave per batch element,
// lane i owns states k1=2i+1, k2=2i+2, skewed schedule (2 columns/step),
// cross-lane via DPP wave_shr:1 with the boundary channel COMPRESSED to
// sender-side dots (4 dot DPPs + 1 sym DPP/step + 1 E DPP/group).
// Range managed by per-lane exponent E (exact power-of-2 rescale per group).
//
// Session plateau analysis (rounds 8-19): per-wave issue floor ~7.5 cyc/inst
// at 1 wave/SIMD (invariant under ILP/independence/DPP-count/pipelining);
// 512 waves x ~13k essential insts / (2 SIMDs/CU x 256 CUs) ~= 103k cyc
// ~= 43 us. v8 (41), v16 (40.8), v19 (41.6) all sit on this floor.

constexpr float LOG2E = 1.4426950408889634f;
constexpr float LN2   = 0.6931471805599453f;

__device__ __forceinline__ float exp2_hw(float x){ return __builtin_amdgcn_exp2f(x); }
__device__ __forceinline__ float log2_hw(float x){ return __builtin_amdgcn_logf(x); }
__device__ __forceinline__ float ldx(float x,int e){ return __builtin_amdgcn_ldexpf(x,e); }
__device__ __forceinline__ int   fxe(float x){ return __builtin_amdgcn_frexp_expf(x); }
// DPP wave_shr:1 — lane i gets lane i-1's src; lane 0 gets old_.
__device__ __forceinline__ int   dppi(int o,int s){ return __builtin_amdgcn_update_dpp(o,s,0x138,0xF,0xF,false); }
__device__ __forceinline__ float dppf(float o,float s){ return __int_as_float(dppi(__float_as_int(o),__float_as_int(s))); }

// One 2-col step: cols c = 2*(SM1+1)-1-2i, c+1.
// Received channels (from lane i-1, row 2i):
//   qdMm: dotM @ col c   -> nM1b path (saved logic per v16)
//   qdMe: dotM @ col c+1 -> saved (pdM), consumed NEXT step
//   qdDm: dotD @ col c   -> nD1;  qdDe: dotD @ col c+1 -> nD1b
// sq = 2^(qE - E) hoisted per 4-step group (E frozen between rescales).
#define STEP(FRESH, ISS1, MASKED, SM1) do {                                    \
    const float qdMm = dppf(0.0f, xdMm);                                       \
    const float qdMe = dppf(0.0f, xdMe);                                       \
    const float qdDm = dppf(0.0f, xdDm);                                       \
    const float qdDe = dppf(0.0f, xdDe);                                       \
    const int   qsym = dppi((FRESH), symq);                                    \
    const float v   = (ISS1) ? q1g : gg * u;       /* fI0[2s-1] */             \
    const float nI1 = fmaf(tmi1, cMx, tii1 * cIx);                             \
    const float nI2 = fmaf(tmi2, cMy, tii2 * cIy);                             \
    float dM_c1 = qdMm * sq;                                                   \
    const float dD_c  = qdDm * sq;     /* lane0: 0*sq = 0 = row-0 dotD */      \
    const float dD_c1 = qdDe * sq;                                             \
    const float dM_sv = qdMe * sq;                                             \
    float dP = pdM;                                                            \
    /* lane-0 virtual row 0: dotM = tmm0*fM0 + tim0*fI0 (fD0-term = 0) */      \
    const float z0 = fmaf(tim0, ldx(u, EI0 - E),                               \
                          (ISS1) ? ldx(tmm0, -E) : 0.0f);                      \
    const float z1 = tim0 * ldx(v, EI0 - E);                                   \
    if (lane0) { dP = z0; dM_c1 = z1; }                                        \
    const bool ba = (qsym & 1) != 0, bb = (qsym & 2) != 0;                     \
    const bool bc = (qsym & 4) != 0, bd = (qsym & 8) != 0;                     \
    const float e1c = bb ? (ba ? el1.w : el1.z) : (ba ? el1.y : el1.x);        \
    const float e2c = bb ? (ba ? el2.w : el2.z) : (ba ? el2.y : el2.x);        \
    const float e1d = bd ? (bc ? el1.w : el1.z) : (bc ? el1.y : el1.x);        \
    const float e2d = bd ? (bc ? el2.w : el2.z) : (bc ? el2.y : el2.x);        \
    /* ---- col c ---- */                                                      \
    const float nM1 = e1c * dP;                                                \
    const float nM2 = e2c * fmaf(tdm1, cDx, fmaf(tim1, cIx, tmm1 * cMx));      \
    const float nD1 = dD_c;                                                    \
    const float nD2 = fmaf(tmd1, nM1, tdd1 * nD1);                             \
    /* ---- col c+1 ---- */                                                    \
    const float nM1b = e1d * dM_c1;                                            \
    const float nI1b = fmaf(tmi1, nM1, tii1 * nI1);                            \
    const float nI2b = fmaf(tmi2, nM2, tii2 * nI2);                            \
    const float nD1b = dD_c1;                                                  \
    const float nM2b = e2d * fmaf(tdm1, nD1, fmaf(tim1, nI1, tmm1 * nM1));     \
    const float nD2b = fmaf(tmd1, nM1b, tdd1 * nD1b);                          \
    /* ---- sender dots for lane i+1 (row 2i+2 coefficients) ---- */           \
    const float ndMm = fmaf(t2mm, nM2,  fmaf(t2im, nI2,  t2dm * nD2));         \
    const float ndMe = fmaf(t2mm, nM2b, fmaf(t2im, nI2b, t2dm * nD2b));        \
    const float ndDm = fmaf(t2md, nM2,  t2dd * nD2);                           \
    const float ndDe = fmaf(t2md, nM2b, t2dd * nD2b);                          \
    /* ---- commit ---- */                                                     \
    xdMm = ndMm; xdDm = ndDm; xdDe = ndDe;  /* consumed only when act */       \
    if (MASKED) {                                                              \
        const bool act = ((unsigned)((SM1) - i)) < 128u;                       \
        cMx = act ? nM1b : cMx;  cMy = act ? nM2b : cMy;                       \
        cIx = act ? nI1b : cIx;  cIy = act ? nI2b : cIy;                       \
        cDx = act ? nD1b : cDx;  cDy = act ? nD2b : cDy;                       \
        xdMe = act ? ndMe : xdMe;   /* pre-active: frozen col-0 end-dot */     \
    } else {                                                                   \
        cMx = nM1b; cMy = nM2b; cIx = nI1b; cIy = nI2b; cDx = nD1b; cDy = nD2b;\
        xdMe = ndMe;                                                           \
    }                                                                          \
    pdM = dM_sv;                                                               \
    symq = qsym;                                                               \
    u = gg * v;                                    /* fI0[2s] */               \
} while (0)

#define RESCALE do {                                                           \
    const float anc = fmaxf(fmaxf(fmaxf(cMx, cMy), fmaxf(cIx, cIy)),           \
                            fmaxf(cDx, cDy));                                  \
    const int e = fxe(anc);                                                    \
    E += e;                                                                    \
    const float sE = ldx(1.0f, -e);                                            \
    cMx *= sE; cMy *= sE; cIx *= sE; cIy *= sE; cDx *= sE; cDy *= sE;          \
    xdMm *= sE; xdMe *= sE; xdDm *= sE; xdDe *= sE; pdM *= sE;                 \
    const int eI = fxe(u); EI0 += eI; u = ldx(u, -eI);                         \
} while (0)

// transitions: (B, 129, 7)  M2M=0 M2I=1 M2D=2 I2M=3 I2I=4 D2M=5 D2D=6
// emissions:   (B, 128, 4);  tokens: (B, 256) int32 in [0,4)
__global__ __launch_bounds__(64, 1) void phmm_fwd(const int* __restrict__ tokens,
                                                  const float* __restrict__ trans,
                                                  const float* __restrict__ emis,
                                                  float* __restrict__ nll_out)
{
    const int b = blockIdx.x;
    const int i = threadIdx.x;
    const bool lane0 = (i == 0);

    const float* ab = trans + (size_t)b * 903;
    const int r0 = (2*i)*7, r1 = (2*i+1)*7, r2 = (2*i+2)*7;

    // Linear-space params.
    const float tmm0 = exp2_hw(ab[r0+0]*LOG2E);      // lane-0 synthesis only
    const float tim0 = exp2_hw(ab[r0+3]*LOG2E);
    const float tmm1 = exp2_hw(ab[r1+0]*LOG2E);
    const float tim1 = exp2_hw(ab[r1+3]*LOG2E);
    const float tdm1 = exp2_hw(ab[r1+5]*LOG2E);
    const float tmd1 = exp2_hw(ab[r1+2]*LOG2E);
    const float tdd1 = exp2_hw(ab[r1+6]*LOG2E);
    const float tmi1 = 0.25f*exp2_hw(ab[r1+1]*LOG2E);
    const float tii1 = 0.25f*exp2_hw(ab[r1+4]*LOG2E);
    const float tmi2 = 0.25f*exp2_hw(ab[r2+1]*LOG2E);
    const float tii2 = 0.25f*exp2_hw(ab[r2+4]*LOG2E);
    // Sender-dot coefficients: row 2i+2 = receiver's (k-1) row.
    const float t2mm = exp2_hw(ab[r2+0]*LOG2E);
    const float t2im = exp2_hw(ab[r2+3]*LOG2E);
    const float t2dm = exp2_hw(ab[r2+5]*LOG2E);
    const float t2md = exp2_hw(ab[r2+2]*LOG2E);
    const float t2dd = exp2_hw(ab[r2+6]*LOG2E);
    const float q1g  = 0.25f*exp2_hw(ab[1]*LOG2E);   // fI0[1]
    const float gg   = 0.25f*exp2_hw(ab[4]*LOG2E);   // fI0 geometric link

    const float4* eb = (const float4*)(emis + (size_t)b*512);
    float4 el1 = eb[2*i], el2 = eb[2*i+1];
    el1.x=exp2_hw(el1.x*LOG2E); el1.y=exp2_hw(el1.y*LOG2E);
    el1.z=exp2_hw(el1.z*LOG2E); el1.w=exp2_hw(el1.w*LOG2E);
    el2.x=exp2_hw(el2.x*LOG2E); el2.y=exp2_hw(el2.y*LOG2E);
    el2.z=exp2_hw(el2.z*LOG2E); el2.w=exp2_hw(el2.w*LOG2E);

    const int4 ts = ((const int4*)(tokens + (size_t)b*256))[i];

    // Col-0 delete chain, closed form (log2 prefix scan).
    const float ldd0 = ab[r0+6]*LOG2E;
    const float ldd1 = ab[r1+6]*LOG2E;
    const float lmd0b = ab[2]*LOG2E;
    float incl = (lane0 ? 0.0f : ldd0) + ldd1;
    #pragma unroll
    for (int d = 1; d < 64; d <<= 1) {
        float t = __shfl_up(incl, d);
        if (i >= d) incl += t;
    }
    float exPre = __shfl_up(incl, 1);
    if (lane0) exPre = 0.0f;
    const float g1 = lmd0b + exPre + (lane0 ? 0.0f : ldd0); // log2 fD[2i+1][0]
    const float g2 = g1 + ldd1;                             // log2 fD[2i+2][0]

    int E = (int)floorf(fmaxf(g1, g2));
    float cMx = 0.0f, cMy = 0.0f, cIx = 0.0f, cIy = 0.0f;
    float cDx = exp2_hw(g1 - (float)E), cDy = exp2_hw(g2 - (float)E);
    // Export regs. xdMe init = col-0 end-dot (fM[2i+2][0]=0, fI=0):
    float xdMm = 0.0f, xdDm = 0.0f, xdDe = 0.0f;
    float xdMe = t2dm * cDy;
    float pdM = 0.0f;                 // never consumed before first real save
    float u = 0.0f; int EI0 = 0;      // fI0 chain (wave-replicated)
    int symq = 0;

    // 48 groups x 4 steps (s = 1..192). Fill g<16 (masked), steady 16..31
    // (mask-free), drain 32..47 (masked, no tokens). qE/sq hoisted per group.
    #pragma unroll 1
    for (int g = 0; g < 16; ++g) {          // FILL
        const int qE = dppi(E, E);
        const float sq = ldx(1.0f, qE - E);
        const int a0 = __builtin_amdgcn_readlane(ts.x, 2*g);
        const int a1 = __builtin_amdgcn_readlane(ts.y, 2*g);
        const int a2 = __builtin_amdgcn_readlane(ts.z, 2*g);
        const int a3 = __builtin_amdgcn_readlane(ts.w, 2*g);
        const int b0 = __builtin_amdgcn_readlane(ts.x, 2*g+1);
        const int b1 = __builtin_amdgcn_readlane(ts.y, 2*g+1);
        const int b2 = __builtin_amdgcn_readlane(ts.z, 2*g+1);
        const int b3 = __builtin_amdgcn_readlane(ts.w, 2*g+1);
        STEP(a0 | (a1 << 2), g == 0, 1, 4*g);
        STEP(a2 | (a3 << 2), false,  1, 4*g + 1);
        STEP(b0 | (b1 << 2), false,  1, 4*g + 2);
        STEP(b2 | (b3 << 2), false,  1, 4*g + 3);
        RESCALE;
    }
    #pragma unroll 1
    for (int g = 16; g < 32; ++g) {         // STEADY (all lanes active)
        const int qE = dppi(E, E);
        const float sq = ldx(1.0f, qE - E);
        const int a0 = __builtin_amdgcn_readlane(ts.x, 2*g);
        const int a1 = __builtin_amdgcn_readlane(ts.y, 2*g);
        const int a2 = __builtin_amdgcn_readlane(ts.z, 2*g);
        const int a3 = __builtin_amdgcn_readlane(ts.w, 2*g);
        const int b0 = __builtin_amdgcn_readlane(ts.x, 2*g+1);
        const int b1 = __builtin_amdgcn_readlane(ts.y, 2*g+1);
        const int b2 = __builtin_amdgcn_readlane(ts.z, 2*g+1);
        const int b3 = __builtin_amdgcn_readlane(ts.w, 2*g+1);
        STEP(a0 | (a1 << 2), false, 0, 4*g);
        STEP(a2 | (a3 << 2), false, 0, 4*g + 1);
        STEP(b0 | (b1 << 2), false, 0, 4*g + 2);
        STEP(b2 | (b3 << 2), false, 0, 4*g + 3);
        RESCALE;
    }
    #pragma unroll 1
    for (int g = 32; g < 48; ++g) {         // DRAIN (no fresh tokens needed)
        const int qE = dppi(E, E);
        const float sq = ldx(1.0f, qE - E);
        STEP(0, false, 1, 4*g);
        STEP(0, false, 1, 4*g + 1);
        STEP(0, false, 1, 4*g + 2);
        STEP(0, false, 1, 4*g + 3);
        RESCALE;
    }

    // lane 63: xdMe (frozen after its last active step, rescales tracked by E)
    // = a[128][M2M]*fM[128][256] + a[128][I2M]*fI + a[128][D2M]*fD = final sum.
    if (i == 63) nll_out[b] = -(log2_hw(xdMe) + (float)E)*LN2;
}

__global__ __launch_bounds__(256) void phmm_finish(const float* __restrict__ nll,
                                                   const float* __restrict__ mus,
                                                   const float* __restrict__ logvars,
                                                   float* __restrict__ out)
{
    const int tid = threadIdx.x;
    float acc = 0.0f;
    for (int idx = tid; idx < 512; idx += 256) acc += nll[idx];
    for (int idx = tid; idx < 8192; idx += 256) {
        const float mu = mus[idx], lv = logvars[idx];
        acc -= 0.5f * (1.0f + lv - mu * mu - exp2_hw(lv * LOG2E));
    }
    #pragma unroll
    for (int off = 32; off >= 1; off >>= 1) acc += __shfl_down(acc, off);
    __shared__ float red[4];
    if ((tid & 63) == 0) red[tid >> 6] = acc;
    __syncthreads();
    if (tid == 0) out[0] = (red[0] + red[1] + red[2] + red[3]) * (1.0f / 512.0f);
}

extern "C" void kernel_launch(void* const* d_in, const int* in_sizes, int n_in,
                              void* d_out, int out_size, void* d_ws, size_t ws_size,
                              hipStream_t stream)
{
    const int*   tokens  = (const int*)d_in[0];   // (512, 256) int32
    const float* trans   = (const float*)d_in[1]; // (512, 129, 7) f32
    const float* emis    = (const float*)d_in[2]; // (512, 128, 4) f32
    const float* mus     = (const float*)d_in[3]; // (512, 16) f32
    const float* logvars = (const float*)d_in[4]; // (512, 16) f32
    float* nll = (float*)d_ws;                    // 512 floats scratch

    phmm_fwd<<<dim3(512), dim3(64), 0, stream>>>(tokens, trans, emis, nll);
    phmm_finish<<<dim3(1), dim3(256), 0, stream>>>(nll, mus, logvars, (float*)d_out);
}